// Round 1
// baseline (185.135 us; speedup 1.0000x reference)
//
#include <hip/hip_runtime.h>

#define EPS 1e-10f

// Computes one batch element's mean (2 floats) and cov (4 floats) entirely in
// registers. All the 2x2 linear algebra (cholesky, triangular solve, inverse,
// quadratic form) is closed-form.
__device__ __forceinline__ void compute_one(
    float xe, float pe, float de, float fe,
    float omega, float lam, float r,
    float mu10, float mu11, float mu20, float mu21,
    float s1a, float s1b, float s1c,
    float s2a, float s2b, float s2c,
    float phi00, float phi01, float phi10, float phi11,
    float sp00, float sp01, float sp11,
    float* m, float* c)
{
    float om = 1.0f - pe;

    // Sigma_bar = p*S1 + (1-p)*S2 + EPS*I  (2x2 symmetric: a b / b c)
    float a  = pe * s1a + om * s2a + EPS;
    float b  = pe * s1b + om * s2b;
    float cc = pe * s1c + om * s2c + EPS;

    // chol (lower): L = [[l00,0],[l10,l11]];  U = L^T (upper)
    float l00 = sqrtf(a);
    float l10 = b / l00;
    float l11 = sqrtf(cc - l10 * l10);
    float inv_l00 = 1.0f / l00;
    float inv_l11 = 1.0f / l11;

    // mu_bar - r
    float mb0 = pe * mu10 + om * mu20 - r;
    float mb1 = pe * mu11 + om * mu21 - r;

    // adj = p - dlnf_dp * p * (1-p);  signal_i = mb_i * (phi_i0*adj + phi_i1)
    float adj  = pe - de * pe * om;
    float sig0 = mb0 * (phi00 * adj + phi01);
    float sig1 = mb1 * (phi10 * adj + phi11);

    // back-substitution: U x = sig, U = [[l00, l10],[0, l11]]
    float sti1 = sig1 * inv_l11;
    float sti0 = (sig0 - l10 * sti1) * inv_l00;

    float nxo = omega - xe;   // -(x - omega)
    m[0] = nxo * sti0;
    m[1] = nxo * sti1;

    // inv_U (upper): [[1/l00, -l10/(l00*l11)],[0, 1/l11]]
    float iu00 = inv_l00;
    float iu11 = inv_l11;
    float iu01 = -(l10 * inv_l00) * inv_l11;

    // C = inv_U @ spd @ inv_U^T   (spd symmetric)
    float M00 = iu00 * sp00 + iu01 * sp01;
    float M01 = iu00 * sp01 + iu01 * sp11;
    float M10 = iu11 * sp01;
    float M11 = iu11 * sp11;
    float C00 = M00 * iu00 + M01 * iu01;
    float C01 = M01 * iu11;
    float C10 = M10 * iu00 + M11 * iu01;
    float C11 = M11 * iu11;

    float scale = 0.5f * lam * fe;
    float off = 0.5f * (scale * C01 + scale * C10);
    c[0] = scale * C00 + EPS;
    c[1] = off;
    c[2] = off;
    c[3] = scale * C11 + EPS;
}

__global__ __launch_bounds__(256) void poemv_kernel(
    const float* __restrict__ x, const float* __restrict__ omega_p,
    const float* __restrict__ p, const float* __restrict__ dlnf_dp,
    const float* __restrict__ f,
    const float* __restrict__ mu1, const float* __restrict__ mu2,
    const float* __restrict__ S1, const float* __restrict__ S2,
    const float* __restrict__ phi, const float* __restrict__ ct,
    const int* __restrict__ lambda_p, const int* __restrict__ r_p,
    float* __restrict__ out_mean, float* __restrict__ out_cov, int B)
{
    int tid = blockIdx.x * blockDim.x + threadIdx.x;
    int b0 = tid * 4;
    if (b0 >= B) return;

    // batch-invariant scalars (uniform addresses -> s_load, L1/sK cached)
    float omega = omega_p[0];
    float lam   = (float)lambda_p[0];
    float r     = (float)r_p[0];
    float mu10 = mu1[0], mu11 = mu1[1];
    float mu20 = mu2[0], mu21 = mu2[1];
    float s1a = S1[0], s1b = S1[2], s1c = S1[3];   // lower triangle (1,0)=idx2
    float s2a = S2[0], s2b = S2[2], s2c = S2[3];
    float phi00 = phi[0], phi01 = phi[1], phi10 = phi[2], phi11 = phi[3];

    // spd_core from cov_tril_unconstrained (batch-invariant):
    // tril = [[exp(ct00),0],[ct10,exp(ct11)]];  spd = tril @ tril^T
    float e0 = expf(ct[0]);
    float e1 = expf(ct[3]);
    float t10 = ct[2];
    float sp00 = e0 * e0;
    float sp01 = t10 * e0;
    float sp11 = t10 * t10 + e1 * e1;

    if (b0 + 3 < B) {
        float4 xv = ((const float4*)x)[tid];
        float4 pv = ((const float4*)p)[tid];
        float4 dv = ((const float4*)dlnf_dp)[tid];
        float4 fv = ((const float4*)f)[tid];

        float m[8];
        float c[16];
        compute_one(xv.x, pv.x, dv.x, fv.x, omega, lam, r, mu10, mu11, mu20, mu21,
                    s1a, s1b, s1c, s2a, s2b, s2c, phi00, phi01, phi10, phi11,
                    sp00, sp01, sp11, m + 0, c + 0);
        compute_one(xv.y, pv.y, dv.y, fv.y, omega, lam, r, mu10, mu11, mu20, mu21,
                    s1a, s1b, s1c, s2a, s2b, s2c, phi00, phi01, phi10, phi11,
                    sp00, sp01, sp11, m + 2, c + 4);
        compute_one(xv.z, pv.z, dv.z, fv.z, omega, lam, r, mu10, mu11, mu20, mu21,
                    s1a, s1b, s1c, s2a, s2b, s2c, phi00, phi01, phi10, phi11,
                    sp00, sp01, sp11, m + 4, c + 8);
        compute_one(xv.w, pv.w, dv.w, fv.w, omega, lam, r, mu10, mu11, mu20, mu21,
                    s1a, s1b, s1c, s2a, s2b, s2c, phi00, phi01, phi10, phi11,
                    sp00, sp01, sp11, m + 6, c + 12);

        // mean: 8 consecutive floats at out_mean + b0*2 (16B aligned)
        float4* mo = (float4*)(out_mean + (size_t)b0 * 2);
        mo[0] = make_float4(m[0], m[1], m[2], m[3]);
        mo[1] = make_float4(m[4], m[5], m[6], m[7]);
        // cov: 16 consecutive floats at out_cov + b0*4 (16B aligned)
        float4* co = (float4*)(out_cov + (size_t)b0 * 4);
        co[0] = make_float4(c[0],  c[1],  c[2],  c[3]);
        co[1] = make_float4(c[4],  c[5],  c[6],  c[7]);
        co[2] = make_float4(c[8],  c[9],  c[10], c[11]);
        co[3] = make_float4(c[12], c[13], c[14], c[15]);
    } else {
        // tail (B % 4 != 0)
        for (int b = b0; b < B; ++b) {
            float m[2], c[4];
            compute_one(x[b], p[b], dlnf_dp[b], f[b], omega, lam, r,
                        mu10, mu11, mu20, mu21, s1a, s1b, s1c, s2a, s2b, s2c,
                        phi00, phi01, phi10, phi11, sp00, sp01, sp11, m, c);
            out_mean[(size_t)b * 2 + 0] = m[0];
            out_mean[(size_t)b * 2 + 1] = m[1];
            out_cov[(size_t)b * 4 + 0] = c[0];
            out_cov[(size_t)b * 4 + 1] = c[1];
            out_cov[(size_t)b * 4 + 2] = c[2];
            out_cov[(size_t)b * 4 + 3] = c[3];
        }
    }
}

extern "C" void kernel_launch(void* const* d_in, const int* in_sizes, int n_in,
                              void* d_out, int out_size, void* d_ws, size_t ws_size,
                              hipStream_t stream) {
    const float* x     = (const float*)d_in[0];
    const float* omega = (const float*)d_in[1];
    const float* p     = (const float*)d_in[2];
    const float* dlnf  = (const float*)d_in[3];
    const float* f     = (const float*)d_in[4];
    const float* mu1   = (const float*)d_in[5];
    const float* mu2   = (const float*)d_in[6];
    const float* S1    = (const float*)d_in[7];
    const float* S2    = (const float*)d_in[8];
    const float* phi   = (const float*)d_in[9];
    const float* ct    = (const float*)d_in[10];
    const int*   lam   = (const int*)d_in[11];
    const int*   r     = (const int*)d_in[12];

    int B = in_sizes[0];
    float* out_mean = (float*)d_out;
    float* out_cov  = out_mean + (size_t)B * 2;

    int n4 = (B + 3) / 4;
    int threads = 256;
    int blocks = (n4 + threads - 1) / threads;
    poemv_kernel<<<blocks, threads, 0, stream>>>(
        x, omega, p, dlnf, f, mu1, mu2, S1, S2, phi, ct, lam, r,
        out_mean, out_cov, B);
}